// Round 9
// baseline (59.506 us; speedup 1.0000x reference)
//
#include <hip/hip_runtime.h>
#include <stdint.h>

#define N 2048
#define F 128
#define UDIM 128

typedef __attribute__((ext_vector_type(8))) __bf16 bf16x8;
typedef __attribute__((ext_vector_type(8))) unsigned short us8;
typedef __attribute__((ext_vector_type(4))) float f32x4;

__device__ __forceinline__ unsigned short f2bf(float f) {
  union { float f; uint32_t u; } v; v.f = f;
  uint32_t u = v.u;
  return (unsigned short)((u + 0x7FFFu + ((u >> 16) & 1u)) >> 16);
}
__device__ __forceinline__ float bf2f(unsigned short u) {
  union { uint32_t u; float f; } v; v.u = ((uint32_t)u) << 16; return v.f;
}
__device__ __forceinline__ uint32_t cvtpk(float lo, float hi) {
  uint32_t r;
  asm("v_cvt_pk_bf16_f32 %0, %1, %2" : "=v"(r) : "v"(lo), "v"(hi));
  return r;
}
__device__ __forceinline__ void async_load16(const void* g, void* l) {
  typedef const __attribute__((address_space(1))) uint32_t* gp_t;
  typedef __attribute__((address_space(3))) uint32_t* lp_t;
  __builtin_amdgcn_global_load_lds((gp_t)(uintptr_t)g, (lp_t)(uint32_t)(uintptr_t)l, 16, 0, 0);
}

// ================ kernel 1: [colsum blocks 0..1023] + [Z=(X@W)^T blocks 1024..1535] ================
__global__ __launch_bounds__(256, 4)
void gcn_pass1(const float* __restrict__ A, const float* __restrict__ X,
               const float* __restrict__ W, float* __restrict__ partial,
               unsigned short* __restrict__ Z) {
  __shared__ __align__(16) unsigned short Wl[128 * 128];  // [u][k] swizzled (xwT role only)
  __shared__ __align__(16) unsigned short Xl[32 * 128];   // [i][k] swizzled

  const int bid = blockIdx.x;
  const int t = threadIdx.x;

  if (bid < 1024) {
    // ---- colsum role: partial[b][rc][j], 32 rows per block ----
    const int b = bid >> 7;
    const int rc = (bid >> 1) & 63;
    const int j = (bid & 1) * 1024 + t * 4;
    const float* ap = A + (size_t)b * N * N + (size_t)rc * 32 * N + j;
    float s0 = 0.f, s1 = 0.f, s2 = 0.f, s3 = 0.f;
    #pragma unroll 4
    for (int rr = 0; rr < 32; ++rr) {
      float4 v = *(const float4*)(ap + (size_t)rr * N);
      s0 += v.x; s1 += v.y; s2 += v.z; s3 += v.w;
    }
    float4 s; s.x = s0; s.y = s1; s.z = s2; s.w = s3;
    *(float4*)&partial[((size_t)b * 64 + rc) * N + j] = s;
    return;
  }

  // ---- xwT role: Z[b,u,i] = (X@W)[i,u] (unscaled), computed transposed ----
  const int zid = bid - 1024;
  const int lane = t & 63;
  const int wid = t >> 6;
  const int b = zid >> 6;
  const int i0 = (zid & 63) << 5;

  {
    const int u = t & 127;
    const int khalf = t >> 7;
    #pragma unroll
    for (int g = 0; g < 8; ++g) {
      const int k0 = khalf * 64 + g * 8;
      float v[8];
      #pragma unroll
      for (int e = 0; e < 8; ++e) v[e] = W[(size_t)(k0 + e) * 128 + u];
      uint4 w;
      w.x = cvtpk(v[0], v[1]); w.y = cvtpk(v[2], v[3]);
      w.z = cvtpk(v[4], v[5]); w.w = cvtpk(v[6], v[7]);
      const int slot = khalf * 8 + g;
      *(uint4*)&Wl[u * 128 + ((slot ^ (u & 7)) * 8)] = w;
    }
  }
  {
    const int r = t >> 3;
    const float* xp = X + ((size_t)b * N + i0 + r) * F + (t & 7) * 8;
    #pragma unroll
    for (int h = 0; h < 2; ++h) {
      float4 v0 = *(const float4*)(xp + h * 64);
      float4 v1 = *(const float4*)(xp + h * 64 + 4);
      uint4 w;
      w.x = cvtpk(v0.x, v0.y); w.y = cvtpk(v0.z, v0.w);
      w.z = cvtpk(v1.x, v1.y); w.w = cvtpk(v1.z, v1.w);
      const int slot = (t & 7) + h * 8;
      *(uint4*)&Xl[r * 128 + ((slot ^ (r & 7)) * 8)] = w;
    }
  }
  __syncthreads();

  f32x4 acc[2][2];
  #pragma unroll
  for (int a = 0; a < 2; ++a)
    #pragma unroll
    for (int c = 0; c < 2; ++c) { f32x4 z = {0.f, 0.f, 0.f, 0.f}; acc[a][c] = z; }

  const int u0 = wid * 32;
  #pragma unroll
  for (int kc = 0; kc < 4; ++kc) {
    bf16x8 af[2], bfv[2];
    #pragma unroll
    for (int ut = 0; ut < 2; ++ut) {
      const int u = u0 + ut * 16 + (lane & 15);
      const int sl = ((kc * 4 + (lane >> 4)) ^ (u & 7)) * 8;
      af[ut] = *(const bf16x8*)&Wl[u * 128 + sl];
    }
    #pragma unroll
    for (int it = 0; it < 2; ++it) {
      const int rr = it * 16 + (lane & 15);
      const int sl = ((kc * 4 + (lane >> 4)) ^ (rr & 7)) * 8;
      bfv[it] = *(const bf16x8*)&Xl[rr * 128 + sl];
    }
    #pragma unroll
    for (int ut = 0; ut < 2; ++ut)
      #pragma unroll
      for (int it = 0; it < 2; ++it)
        acc[ut][it] = __builtin_amdgcn_mfma_f32_16x16x32_bf16(af[ut], bfv[it], acc[ut][it], 0, 0, 0);
  }

  #pragma unroll
  for (int ut = 0; ut < 2; ++ut)
    #pragma unroll
    for (int it = 0; it < 2; ++it) {
      const int ic = i0 + it * 16 + (lane & 15);
      #pragma unroll
      for (int rg = 0; rg < 4; ++rg) {
        const int u = u0 + ut * 16 + (lane >> 4) * 4 + rg;
        Z[((size_t)b * UDIM + u) * N + ic] = f2bf(acc[ut][it][rg]);
      }
    }
}

// ================ kernel 2: kcl[b,j] = k^{-1/4} from partial (tiny, L2-resident) ================
__global__ __launch_bounds__(256, 4)
void gcn_kcl(const float* __restrict__ partial, const float* __restrict__ pptr,
             float* __restrict__ kcl) {
  const int t = threadIdx.x;
  const int b = blockIdx.x >> 3;
  const int jj = (blockIdx.x & 7) * 256 + t;
  float s = 0.f;
  #pragma unroll 8
  for (int rc = 0; rc < 64; ++rc)
    s += partial[((size_t)b * 64 + rc) * N + jj];
  const float sp = 1.0f / (1.0f + __expf(-pptr[0]));
  const float k = sp + (1.0f - sp) * s;
  float rv = rsqrtf(sqrtf(k));            // k^(-0.25)
  if (isinf(rv)) rv = 0.f;
  kcl[b * N + jj] = rv;
}

// ================ kernel 3: out = relu(kc_i * (A@(kc.*Z) + qs*kc_i*Z_i) + bias) ================
// 512 threads, M-tile 64 x U 128, 256 blocks. Waves 2x4 (each 32x32).
// 3 LDS buffers; A 3 steps ahead (2 reg sets), Y 2 ahead; steady vmcnt(4).
__global__ __launch_bounds__(512, 2)
void gcn_gemm(const float* __restrict__ A, const unsigned short* __restrict__ Z,
              const float* __restrict__ kcl, const float* __restrict__ bias,
              const float* __restrict__ qptr, float* __restrict__ out) {
  __shared__ __align__(16) unsigned short Abuf[3 * 64 * 64];    // 24 KB, swizzled
  __shared__ __align__(16) unsigned short Ybuf[3 * 128 * 64];   // 48 KB, swizzled
  __shared__ __align__(16) float kcs[2048];                     // 8 KB

  const int t = threadIdx.x;
  const int lane = t & 63;
  const int wid = t >> 6;        // 0..7
  const int wr = wid >> 2;       // 0..1  (M half)
  const int wc = wid & 3;        // 0..3  (U quarter)

  const int bid = blockIdx.x;
  const int b = bid & 7;             // XCD-aware: batch b -> XCD b
  const int i0 = (bid >> 3) << 6;    // m-tile of 64 rows

  const float qs = 1.0f / (1.0f + __expf(-qptr[0]));

  const int r = t >> 3;              // A-staging row (0..63)
  const int c8 = t & 7;              // 8-float column chunk
  const float* Ap = A + (size_t)b * N * N + (size_t)(i0 + r) * N + c8 * 8;
  const unsigned short* Zb = Z + (size_t)b * UDIM * N;

  const int a_woff = r * 64 + ((c8 ^ (r & 7)) * 8);   // swizzled ds_write slot (ushort)
  const int y_u = t >> 3;                             // + rnd*64
  const int y_wavebase = (t & ~63) * 8;

  // stage kc tile (fp32, linear)
  {
    float4 v0 = *(const float4*)&kcl[b * N + t * 4];
    *(float4*)&kcs[t * 4] = v0;
  }
  __syncthreads();

  f32x4 acc[2][2];
  #pragma unroll
  for (int mf = 0; mf < 2; ++mf)
    #pragma unroll
    for (int uf = 0; uf < 2; ++uf) { f32x4 z = {0.f, 0.f, 0.f, 0.f}; acc[mf][uf] = z; }

  float4 a0A, a1A, a0B, a1B;   // reg set = K-tile index parity (even=A, odd=B)

  auto issueY = [&](int kt, int buf) {
    const int k0 = kt * 64;
    #pragma unroll
    for (int rnd = 0; rnd < 2; ++rnd) {
      const int u = rnd * 64 + y_u;
      const int c16 = (t & 7) ^ (u & 7);
      async_load16(Zb + (size_t)u * N + k0 + c16 * 8, &Ybuf[buf * 8192 + rnd * 4096 + y_wavebase]);
    }
  };
  auto compute = [&](int cur) {
    const unsigned short* Ac = Abuf + cur * 4096;
    const unsigned short* Yc = Ybuf + cur * 8192;
    #pragma unroll
    for (int kk = 0; kk < 2; ++kk) {
      bf16x8 af[2], bfv[2];
      #pragma unroll
      for (int mf = 0; mf < 2; ++mf) {
        const int ar = 32 * wr + mf * 16 + (lane & 15);
        const int as = ((kk * 4 + (lane >> 4)) ^ (ar & 7)) * 8;
        af[mf] = *(const bf16x8*)&Ac[ar * 64 + as];
      }
      #pragma unroll
      for (int uf = 0; uf < 2; ++uf) {
        const int u = 32 * wc + uf * 16 + (lane & 15);
        const int bs = ((kk * 4 + (lane >> 4)) ^ (u & 7)) * 8;
        bfv[uf] = *(const bf16x8*)&Yc[u * 64 + bs];
      }
      #pragma unroll
      for (int mf = 0; mf < 2; ++mf)
        #pragma unroll
        for (int uf = 0; uf < 2; ++uf)
          acc[mf][uf] = __builtin_amdgcn_mfma_f32_16x16x32_bf16(af[mf], bfv[uf], acc[mf][uf], 0, 0, 0);
    }
  };

#define SB __builtin_amdgcn_sched_barrier(0)
#define ISSUE_A(KT, R0, R1) { R0 = *(const float4*)(Ap + (KT) * 64); R1 = *(const float4*)(Ap + (KT) * 64 + 4); }
#define CVT_A(BUF, R0, R1, K0) { \
    float4 kj0 = *(const float4*)&kcs[(K0) + c8 * 8]; \
    float4 kj1 = *(const float4*)&kcs[(K0) + c8 * 8 + 4]; \
    uint4 w; \
    w.x = cvtpk(R0.x * kj0.x, R0.y * kj0.y); \
    w.y = cvtpk(R0.z * kj0.z, R0.w * kj0.w); \
    w.z = cvtpk(R1.x * kj1.x, R1.y * kj1.y); \
    w.w = cvtpk(R1.z * kj1.z, R1.w * kj1.w); \
    *(uint4*)&Abuf[(BUF) * 4096 + a_woff] = w; }

  asm volatile("s_waitcnt vmcnt(0) lgkmcnt(0)" ::: "memory");

  // ---- prologue ----  (queue: A=2 insts/tile, Y=2 insts/tile)
  ISSUE_A(0, a0A, a1A); SB;            // [A0]            (2)
  ISSUE_A(1, a0B, a1B); SB;            // [A0 A1]         (4)
  issueY(0, 0); SB;                    // [A0 A1 Y0]      (6)
  asm volatile("s_waitcnt vmcnt(4)" ::: "memory");   // retire A0
  CVT_A(0, a0A, a1A, 0); SB;
  ISSUE_A(2, a0A, a1A); SB;            // [A1 Y0 A2]      (6)
  issueY(1, 1); SB;                    // [A1 Y0 A2 Y1]   (8)

  // invariant entering step kt: [A(kt+1) Y(kt) A(kt+2) Y(kt+1)] = 8 insts
#define GSTEP(KT, VM, R0, R1, DO_A, DO_Y)                          \
  {                                                                \
    asm volatile("s_waitcnt vmcnt(" #VM ")" ::: "memory");         \
    CVT_A(((KT) + 1) % 3, R0, R1, ((KT) + 1) * 64);                \
    asm volatile("s_waitcnt lgkmcnt(0)" ::: "memory");             \
    __builtin_amdgcn_s_barrier(); SB;                              \
    if (DO_A) { ISSUE_A((KT) + 3, R0, R1); } SB;                   \
    if (DO_Y) { issueY((KT) + 2, ((KT) + 2) % 3); } SB;            \
    __builtin_amdgcn_s_setprio(1);                                 \
    compute((KT) % 3);                                             \
    __builtin_amdgcn_s_setprio(0); SB;                             \
  }

  #pragma unroll 1
  for (int kt = 0; kt < 28; kt += 2) {
    GSTEP(kt,     4, a0B, a1B, true, true);     // converts A(kt+1) (odd -> set B)
    GSTEP(kt + 1, 4, a0A, a1A, true, true);     // converts A(kt+2) (even -> set A)
  }
  GSTEP(28, 4, a0B, a1B, true, true);           // cvt A29, issue A31(setB)+Y30
  GSTEP(29, 4, a0A, a1A, false, true);          // cvt A30, issue Y31 (buf 1)
  // step 30: retire A31+Y30
  asm volatile("s_waitcnt vmcnt(2)" ::: "memory");
  CVT_A(1, a0B, a1B, 31 * 64);                  // A31 -> buf 31%3=1
  asm volatile("s_waitcnt lgkmcnt(0)" ::: "memory");
  __builtin_amdgcn_s_barrier(); SB;
  compute(0);                                   // kt=30 -> buf 0
  // step 31
  asm volatile("s_waitcnt vmcnt(0)" ::: "memory");
  __builtin_amdgcn_s_barrier(); SB;
  compute(1);
#undef GSTEP
#undef CVT_A
#undef ISSUE_A
#undef SB

  // epilogue: out = kc_i*acc + qs*kc_i^2*Z_i + bias, relu
  #pragma unroll
  for (int mf = 0; mf < 2; ++mf) {
    const int irow = i0 + 32 * wr + mf * 16 + (lane >> 4) * 4;
    #pragma unroll
    for (int uf = 0; uf < 2; ++uf) {
      const int u = 32 * wc + uf * 16 + (lane & 15);
      const float bv = bias[u];
      #pragma unroll
      for (int rg = 0; rg < 4; ++rg) {
        const int i = irow + rg;
        const float zv = bf2f(Zb[(size_t)u * N + i]);
        const float kv = kcs[i];
        float vv = kv * acc[mf][uf][rg] + qs * kv * kv * zv + bv;
        out[((size_t)b * N + i) * UDIM + u] = vv > 0.f ? vv : 0.f;
      }
    }
  }
}

extern "C" void kernel_launch(void* const* d_in, const int* in_sizes, int n_in,
                              void* d_out, int out_size, void* d_ws, size_t ws_size,
                              hipStream_t stream) {
  (void)in_sizes; (void)n_in; (void)out_size; (void)ws_size;
  const float* A    = (const float*)d_in[0];
  const float* X    = (const float*)d_in[1];
  const float* W    = (const float*)d_in[2];
  const float* bias = (const float*)d_in[3];
  const float* p    = (const float*)d_in[4];
  const float* q    = (const float*)d_in[5];
  float* out = (float*)d_out;

  char* ws = (char*)d_ws;
  float* partial      = (float*)ws;                          // [8][64][2048] f32 = 4 MB
  float* kcl          = (float*)(ws + 4194304);              // 64 KB
  unsigned short* Zb  = (unsigned short*)(ws + 4259840);     // 4 MB

  gcn_pass1<<<dim3(1536), dim3(256), 0, stream>>>(A, X, W, partial, Zb);
  gcn_kcl<<<dim3(64), dim3(256), 0, stream>>>(partial, p, kcl);
  gcn_gemm<<<dim3(256), dim3(512), 0, stream>>>(A, Zb, kcl, bias, q, out);
}

// Round 11
// 57.198 us; speedup vs baseline: 1.0404x; 1.0404x over previous
//
#include <hip/hip_runtime.h>
#include <stdint.h>

#define N 2048
#define F 128
#define UDIM 128

typedef __attribute__((ext_vector_type(8))) __bf16 bf16x8;
typedef __attribute__((ext_vector_type(8))) unsigned short us8;
typedef __attribute__((ext_vector_type(4))) float f32x4;

__device__ __forceinline__ unsigned short f2bf(float f) {
  union { float f; uint32_t u; } v; v.f = f;
  uint32_t u = v.u;
  return (unsigned short)((u + 0x7FFFu + ((u >> 16) & 1u)) >> 16);
}
__device__ __forceinline__ float bf2f(unsigned short u) {
  union { uint32_t u; float f; } v; v.u = ((uint32_t)u) << 16; return v.f;
}
__device__ __forceinline__ uint32_t cvtpk(float lo, float hi) {
  uint32_t r;
  asm("v_cvt_pk_bf16_f32 %0, %1, %2" : "=v"(r) : "v"(lo), "v"(hi));
  return r;
}
__device__ __forceinline__ void async_load16(const void* g, void* l) {
  typedef const __attribute__((address_space(1))) uint32_t* gp_t;
  typedef __attribute__((address_space(3))) uint32_t* lp_t;
  __builtin_amdgcn_global_load_lds((gp_t)(uintptr_t)g, (lp_t)(uint32_t)(uintptr_t)l, 16, 0, 0);
}

// ================ kernel 1: [colsum blocks 0..1023] + [Z=(X@W)^T blocks 1024..1535] ================
__global__ __launch_bounds__(256, 4)
void gcn_pass1(const float* __restrict__ A, const float* __restrict__ X,
               const float* __restrict__ W, float* __restrict__ partial,
               unsigned short* __restrict__ Z) {
  __shared__ __align__(16) unsigned short Wl[128 * 128];  // [u][k] swizzled (xwT role only)
  __shared__ __align__(16) unsigned short Xl[32 * 128];   // [i][k] swizzled

  const int bid = blockIdx.x;
  const int t = threadIdx.x;

  if (bid < 1024) {
    // ---- colsum role: partial[b][rc][j], 32 rows per block ----
    const int b = bid >> 7;
    const int rc = (bid >> 1) & 63;
    const int j = (bid & 1) * 1024 + t * 4;
    const float* ap = A + (size_t)b * N * N + (size_t)rc * 32 * N + j;
    float s0 = 0.f, s1 = 0.f, s2 = 0.f, s3 = 0.f;
    #pragma unroll 8
    for (int rr = 0; rr < 32; ++rr) {
      float4 v = *(const float4*)(ap + (size_t)rr * N);
      s0 += v.x; s1 += v.y; s2 += v.z; s3 += v.w;
    }
    float4 s; s.x = s0; s.y = s1; s.z = s2; s.w = s3;
    *(float4*)&partial[((size_t)b * 64 + rc) * N + j] = s;
    return;
  }

  // ---- xwT role: Z[b,u,i] = (X@W)[i,u] (unscaled), computed transposed ----
  const int zid = bid - 1024;
  const int lane = t & 63;
  const int wid = t >> 6;
  const int b = zid >> 6;
  const int i0 = (zid & 63) << 5;

  {
    const int u = t & 127;
    const int khalf = t >> 7;
    #pragma unroll
    for (int g = 0; g < 8; ++g) {
      const int k0 = khalf * 64 + g * 8;
      float v[8];
      #pragma unroll
      for (int e = 0; e < 8; ++e) v[e] = W[(size_t)(k0 + e) * 128 + u];
      uint4 w;
      w.x = cvtpk(v[0], v[1]); w.y = cvtpk(v[2], v[3]);
      w.z = cvtpk(v[4], v[5]); w.w = cvtpk(v[6], v[7]);
      const int slot = khalf * 8 + g;
      *(uint4*)&Wl[u * 128 + ((slot ^ (u & 7)) * 8)] = w;
    }
  }
  {
    const int r = t >> 3;
    const float* xp = X + ((size_t)b * N + i0 + r) * F + (t & 7) * 8;
    #pragma unroll
    for (int h = 0; h < 2; ++h) {
      float4 v0 = *(const float4*)(xp + h * 64);
      float4 v1 = *(const float4*)(xp + h * 64 + 4);
      uint4 w;
      w.x = cvtpk(v0.x, v0.y); w.y = cvtpk(v0.z, v0.w);
      w.z = cvtpk(v1.x, v1.y); w.w = cvtpk(v1.z, v1.w);
      const int slot = (t & 7) + h * 8;
      *(uint4*)&Xl[r * 128 + ((slot ^ (r & 7)) * 8)] = w;
    }
  }
  __syncthreads();

  f32x4 acc[2][2];
  #pragma unroll
  for (int a = 0; a < 2; ++a)
    #pragma unroll
    for (int c = 0; c < 2; ++c) { f32x4 z = {0.f, 0.f, 0.f, 0.f}; acc[a][c] = z; }

  const int u0 = wid * 32;
  #pragma unroll
  for (int kc = 0; kc < 4; ++kc) {
    bf16x8 af[2], bfv[2];
    #pragma unroll
    for (int ut = 0; ut < 2; ++ut) {
      const int u = u0 + ut * 16 + (lane & 15);
      const int sl = ((kc * 4 + (lane >> 4)) ^ (u & 7)) * 8;
      af[ut] = *(const bf16x8*)&Wl[u * 128 + sl];
    }
    #pragma unroll
    for (int it = 0; it < 2; ++it) {
      const int rr = it * 16 + (lane & 15);
      const int sl = ((kc * 4 + (lane >> 4)) ^ (rr & 7)) * 8;
      bfv[it] = *(const bf16x8*)&Xl[rr * 128 + sl];
    }
    #pragma unroll
    for (int ut = 0; ut < 2; ++ut)
      #pragma unroll
      for (int it = 0; it < 2; ++it)
        acc[ut][it] = __builtin_amdgcn_mfma_f32_16x16x32_bf16(af[ut], bfv[it], acc[ut][it], 0, 0, 0);
  }

  #pragma unroll
  for (int ut = 0; ut < 2; ++ut)
    #pragma unroll
    for (int it = 0; it < 2; ++it) {
      const int ic = i0 + it * 16 + (lane & 15);
      #pragma unroll
      for (int rg = 0; rg < 4; ++rg) {
        const int u = u0 + ut * 16 + (lane >> 4) * 4 + rg;
        Z[((size_t)b * UDIM + u) * N + ic] = f2bf(acc[ut][it][rg]);
      }
    }
}

// ================ kernel 2: kcl[b,j] = k^{-1/4} from partial (tiny, L2-resident) ================
__global__ __launch_bounds__(256, 4)
void gcn_kcl(const float* __restrict__ partial, const float* __restrict__ pptr,
             float* __restrict__ kcl) {
  const int t = threadIdx.x;
  const int b = blockIdx.x >> 3;
  const int jj = (blockIdx.x & 7) * 256 + t;
  float s = 0.f;
  #pragma unroll 8
  for (int rc = 0; rc < 64; ++rc)
    s += partial[((size_t)b * 64 + rc) * N + jj];
  const float sp = 1.0f / (1.0f + __expf(-pptr[0]));
  const float k = sp + (1.0f - sp) * s;
  float rv = rsqrtf(sqrtf(k));            // k^(-0.25)
  if (isinf(rv)) rv = 0.f;
  kcl[b * N + jj] = rv;
}

// ================ kernel 3: out = relu(kc_i * (A@(kc.*Z) + qs*kc_i*Z_i) + bias) ================
// kc_j folded into the A-operand during reg-staged fp32->bf16 conversion (kc tile in LDS).
// 3 LDS buffers; A issued 3 steps ahead (2 reg sets), Y 2 ahead; steady vmcnt(6).
__global__ __launch_bounds__(256, 2)
void gcn_gemm(const float* __restrict__ A, const unsigned short* __restrict__ Z,
              const float* __restrict__ kcl, const float* __restrict__ bias,
              const float* __restrict__ qptr, float* __restrict__ out) {
  __shared__ __align__(16) unsigned short Abuf[3 * 32 * 64];    // 12 KB, swizzled
  __shared__ __align__(16) unsigned short Ybuf[3 * 128 * 64];   // 48 KB, swizzled
  __shared__ __align__(16) float kcs[2048];                     // 8 KB

  const int t = threadIdx.x;
  const int lane = t & 63;
  const int wid = t >> 6;
  const int wr = wid >> 1;
  const int wc = wid & 1;

  const int bid = blockIdx.x;
  const int b = bid & 7;             // XCD-aware: batch b -> XCD b
  const int i0 = (bid >> 3) << 5;

  const float qs = 1.0f / (1.0f + __expf(-qptr[0]));

  const int r = t >> 3;
  const int c8 = t & 7;
  const float* Ap = A + (size_t)b * N * N + (size_t)(i0 + r) * N + c8 * 8;
  const unsigned short* Zb = Z + (size_t)b * UDIM * N;

  const int a_woff = r * 64 + ((c8 ^ (r & 7)) * 8);
  const int y_u = t >> 3;
  const int y_wavebase = (t & ~63) * 8;

  // stage kc tile (fp32, linear)
  {
    float4 v0 = *(const float4*)&kcl[b * N + t * 8];
    float4 v1 = *(const float4*)&kcl[b * N + t * 8 + 4];
    *(float4*)&kcs[t * 8] = v0;
    *(float4*)&kcs[t * 8 + 4] = v1;
  }
  __syncthreads();

  f32x4 acc[4];
  #pragma unroll
  for (int i = 0; i < 4; ++i) { f32x4 z = {0.f, 0.f, 0.f, 0.f}; acc[i] = z; }

  float4 a0A, a1A, a0B, a1B;   // reg set = K-tile index parity

  auto issueY = [&](int kt, int buf) {
    const int k0 = kt * 64;
    #pragma unroll
    for (int rnd = 0; rnd < 4; ++rnd) {
      const int u = rnd * 32 + y_u;
      const int c16 = (t & 7) ^ (u & 7);
      async_load16(Zb + (size_t)u * N + k0 + c16 * 8, &Ybuf[buf * 8192 + rnd * 2048 + y_wavebase]);
    }
  };
  auto compute = [&](int cur) {
    const unsigned short* Ac = Abuf + cur * 2048;
    const unsigned short* Yc = Ybuf + cur * 8192;
    #pragma unroll
    for (int kk = 0; kk < 2; ++kk) {
      const int ar = 16 * wr + (lane & 15);
      const int as = ((kk * 4 + (lane >> 4)) ^ (ar & 7)) * 8;
      bf16x8 af = *(const bf16x8*)&Ac[ar * 64 + as];
      #pragma unroll
      for (int ut = 0; ut < 4; ++ut) {
        const int u = 64 * wc + ut * 16 + (lane & 15);
        const int bs = ((kk * 4 + (lane >> 4)) ^ (u & 7)) * 8;
        bf16x8 bfv = *(const bf16x8*)&Yc[u * 64 + bs];
        acc[ut] = __builtin_amdgcn_mfma_f32_16x16x32_bf16(af, bfv, acc[ut], 0, 0, 0);
      }
    }
  };

#define SB __builtin_amdgcn_sched_barrier(0)
#define ISSUE_A(KT, R0, R1) { R0 = *(const float4*)(Ap + (KT) * 64); R1 = *(const float4*)(Ap + (KT) * 64 + 4); }
#define CVT_A(BUF, R0, R1, K0) { \
    float4 kj0 = *(const float4*)&kcs[(K0) + c8 * 8]; \
    float4 kj1 = *(const float4*)&kcs[(K0) + c8 * 8 + 4]; \
    uint4 w; \
    w.x = cvtpk(R0.x * kj0.x, R0.y * kj0.y); \
    w.y = cvtpk(R0.z * kj0.z, R0.w * kj0.w); \
    w.z = cvtpk(R1.x * kj1.x, R1.y * kj1.y); \
    w.w = cvtpk(R1.z * kj1.z, R1.w * kj1.w); \
    *(uint4*)&Abuf[(BUF) * 2048 + a_woff] = w; }

  asm volatile("s_waitcnt vmcnt(0) lgkmcnt(0)" ::: "memory");

  // ---- prologue ----
  ISSUE_A(0, a0A, a1A); SB;            // queue: A0(2)
  ISSUE_A(1, a0B, a1B); SB;            // A0 A1 (4)
  issueY(0, 0); SB;                    // A0 A1 Y0 (8)
  asm volatile("s_waitcnt vmcnt(6)" ::: "memory");   // retire A0
  CVT_A(0, a0A, a1A, 0); SB;
  ISSUE_A(2, a0A, a1A); SB;            // A1 Y0 A2 (8)
  issueY(1, 1); SB;                    // A1 Y0 A2 Y1 (12)

#define GSTEP(KT, VM, R0, R1, DO_A, DO_Y)                          \
  {                                                                \
    asm volatile("s_waitcnt vmcnt(" #VM ")" ::: "memory");         \
    CVT_A(((KT) + 1) % 3, R0, R1, ((KT) + 1) * 64);                \
    asm volatile("s_waitcnt lgkmcnt(0)" ::: "memory");             \
    __builtin_amdgcn_s_barrier(); SB;                              \
    if (DO_A) { ISSUE_A((KT) + 3, R0, R1); } SB;                   \
    if (DO_Y) { issueY((KT) + 2, ((KT) + 2) % 3); } SB;            \
    __builtin_amdgcn_s_setprio(1);                                 \
    compute((KT) % 3);                                             \
    __builtin_amdgcn_s_setprio(0); SB;                             \
  }

  #pragma unroll 1
  for (int kt = 0; kt < 28; kt += 2) {
    GSTEP(kt,     6, a0B, a1B, true, true);     // converts A(kt+1) (odd -> set B)
    GSTEP(kt + 1, 6, a0A, a1A, true, true);     // converts A(kt+2) (even -> set A)
  }
  GSTEP(28, 6, a0B, a1B, true, true);           // cvt A29, issue A31(setB)+Y30
  GSTEP(29, 6, a0A, a1A, false, true);          // cvt A30, issue Y31 (buf 1)
  // step 30: retire A31+Y30
  asm volatile("s_waitcnt vmcnt(4)" ::: "memory");
  CVT_A(1, a0B, a1B, 31 * 64);                  // A31 -> buf 31%3=1
  asm volatile("s_waitcnt lgkmcnt(0)" ::: "memory");
  __builtin_amdgcn_s_barrier(); SB;
  compute(0);                                   // kt=30 -> buf 0
  // step 31
  asm volatile("s_waitcnt vmcnt(0)" ::: "memory");
  __builtin_amdgcn_s_barrier(); SB;
  compute(1);
#undef GSTEP
#undef CVT_A
#undef ISSUE_A
#undef SB

  // epilogue: out = kc_i*acc + qs*kc_i^2*Z_i + bias, relu  (Z reads vectorized: ushort4)
  const int irow = i0 + 16 * wr + (lane >> 4) * 4;
  #pragma unroll
  for (int ut = 0; ut < 4; ++ut) {
    const int u = 64 * wc + ut * 16 + (lane & 15);
    const float bv = bias[u];
    const ushort4 zv4 = *(const ushort4*)&Zb[(size_t)u * N + irow];
    #pragma unroll
    for (int rg = 0; rg < 4; ++rg) {
      const int i = irow + rg;
      const float zv = bf2f(rg == 0 ? zv4.x : rg == 1 ? zv4.y : rg == 2 ? zv4.z : zv4.w);
      const float kv = kcs[i];
      float vv = kv * acc[ut][rg] + qs * kv * kv * zv + bv;
      out[((size_t)b * N + i) * UDIM + u] = vv > 0.f ? vv : 0.f;
    }
  }
}

extern "C" void kernel_launch(void* const* d_in, const int* in_sizes, int n_in,
                              void* d_out, int out_size, void* d_ws, size_t ws_size,
                              hipStream_t stream) {
  (void)in_sizes; (void)n_in; (void)out_size; (void)ws_size;
  const float* A    = (const float*)d_in[0];
  const float* X    = (const float*)d_in[1];
  const float* W    = (const float*)d_in[2];
  const float* bias = (const float*)d_in[3];
  const float* p    = (const float*)d_in[4];
  const float* q    = (const float*)d_in[5];
  float* out = (float*)d_out;

  char* ws = (char*)d_ws;
  float* partial      = (float*)ws;                          // [8][64][2048] f32 = 4 MB
  float* kcl          = (float*)(ws + 4194304);              // 64 KB
  unsigned short* Zb  = (unsigned short*)(ws + 4259840);     // 4 MB

  gcn_pass1<<<dim3(1536), dim3(256), 0, stream>>>(A, X, W, partial, Zb);
  gcn_kcl<<<dim3(64), dim3(256), 0, stream>>>(partial, p, kcl);
  gcn_gemm<<<dim3(512), dim3(256), 0, stream>>>(A, Zb, kcl, bias, q, out);
}